// Round 4
// baseline (136.790 us; speedup 1.0000x reference)
//
#include <hip/hip_runtime.h>
#include <math.h>

#define N_ORB   1024
#define NTIMES  1024
#define N_FZ    24
#define N_KEZ   6
#define N_TINT  64
#define N_ALPHA 512

// Workspace:
//   gT : [N_FZ][N_ALPHA][N_TINT] float  = 3,145,728 B  (grid slice, transposed)
//   Pc : [NTIMES][N_ORB] float2         = 8,388,608 B  {u = s + dalpha, dMagEff}
#define GT_BYTES (N_FZ * N_ALPHA * N_TINT * 4)

// ---------------------------------------------------------------------------
// Kernel 1: fused staging. Blocks 0..191: gT transpose (64tint x 64s tile).
// Blocks 192..1215: Pc build from alpha/dMag, 32x32 (o,t) LDS transpose.
// ---------------------------------------------------------------------------
__global__ __launch_bounds__(256) void stage_inputs(
    const float* __restrict__ grid, const float* __restrict__ kEZs,
    const float* __restrict__ kEZ_val_p, const float* __restrict__ alpha,
    const float* __restrict__ dMag, const float* __restrict__ alphas,
    float* __restrict__ gT, float2* __restrict__ Pc)
{
    __shared__ float lds[64 * 65];          // gT branch; Pc branch aliases

    int b = blockIdx.x;
    if (b < 192) {
        // ---- gT[fz][s][tint] = grid[fz][kez][tint][s] ----
        float kv = kEZ_val_p[0];
        int cnt = 0;
#pragma unroll
        for (int i = 0; i < N_KEZ; ++i) cnt += (kEZs[i] <= kv) ? 1 : 0;
        int kez = cnt - 1;                   // searchsorted(right) - 1
        kez = kez < 0 ? 0 : (kez > N_KEZ - 1 ? N_KEZ - 1 : kez);

        int fz = b >> 3, sc = b & 7;
        int w = threadIdx.x >> 6, lane = threadIdx.x & 63;
        const float* gsrc = grid + ((size_t)fz * N_KEZ + kez) * N_TINT * N_ALPHA;

#pragma unroll
        for (int r = 0; r < 16; ++r) {
            int tint = w * 16 + r;
            lds[tint * 65 + lane] = gsrc[(size_t)tint * N_ALPHA + sc * 64 + lane];
        }
        __syncthreads();
#pragma unroll
        for (int r = 0; r < 16; ++r) {
            int sl = w * 16 + r;
            gT[((size_t)fz * N_ALPHA + sc * 64 + sl) * N_TINT + lane] = lds[lane * 65 + sl];
        }
    } else {
        // ---- Pc[t][o] = {u, dmEff}, 32x32 tile ----
        float* ut = lds;                     // [32][33]
        float* dt = lds + 1056;

        int u = b - 192;                     // 0..1023
        int t0 = (u & 31) * 32, o0 = (u >> 5) * 32;
        int row = threadIdx.x >> 5, col = threadIdx.x & 31;

        float al0 = alphas[0], al1 = alphas[N_ALPHA - 1];
        float la0 = log10f(al0);
        float inv_step = 1.0f / (log10f(alphas[1]) - la0);

#pragma unroll
        for (int r = 0; r < 4; ++r) {
            int ol = r * 8 + row;
            size_t idx = (size_t)(o0 + ol) * NTIMES + t0 + col;
            float a = alpha[idx];
            float d = dMag[idx];
            float a_ind = (log10f(a) - la0) * inv_step;
            int a0i = (int)a_ind;            // trunc toward zero == astype(int32)
            a0i = a0i < 0 ? 0 : (a0i > N_ALPHA - 1 ? N_ALPHA - 1 : a0i);
            float dal = a_ind - (float)a0i;  // vs clipped a0 (faithful)
            int s = a0i > N_ALPHA - 2 ? N_ALPHA - 2 : a0i;   // dynamic_slice clamp
            bool geom = (a >= al0) && (a <= al1);
            // u = s + dal reproduces dim = g[s] + (u-s)*dg exactly (mod ~3e-5 pack err)
            float uv = (float)s + dal;
            uv = fminf(fmaxf(uv, 0.0f), 510.999f);
            if (!geom) uv = 0.0f;            // dead: dm=INF kills it; keep index safe
            ut[ol * 33 + col] = uv;
            dt[ol * 33 + col] = geom ? d : __builtin_inff();
        }
        __syncthreads();
#pragma unroll
        for (int r = 0; r < 4; ++r) {
            int tl = r * 8 + row;
            float2 v;
            v.x = ut[col * 33 + tl];
            v.y = dt[col * 33 + tl];
            Pc[(size_t)(t0 + tl) * N_ORB + o0 + col] = v;
        }
    }
}

// ---------------------------------------------------------------------------
// Kernel 2: one block per t.
// Phase A: counting-sort the 1024 orbits by s=(int)u into LDS (float2, 8 KB).
// Phase B: lane = tint. Wave w walks sorted range [w*256, w*256+256)
// ORBIT-SERIALLY: per-orbit data is an LDS broadcast (uniform value), the
// row index is scalarized via readfirstlane -> uniform s_cbranch row reload,
// rows load once per row-change as coalesced 256 B dwords, s==cur+1 reuses
// g1 as new g0. Per orbit: ~6 VALU inst for 64 tint-compares.
// ---------------------------------------------------------------------------
__global__ __launch_bounds__(256) void pdet_main(
    const float* __restrict__ fZ_vals, const float* __restrict__ fZs,
    const float* __restrict__ gT, const float2* __restrict__ Pc,
    float* __restrict__ out)
{
    __shared__ float2 Psort[N_ORB];      // 8 KB sorted {u, dmEff}
    __shared__ int    hist[512];
    __shared__ int    histPS[512];
    __shared__ int    red[4 * 64];

    int t = blockIdx.x;
    int tid = threadIdx.x;
    int w = tid >> 6, lane = tid & 63;

    float lf0 = log10f(fZs[0]);
    float inv_f = 1.0f / (log10f(fZs[1]) - lf0);
    float fi = (log10f(fZ_vals[t]) - lf0) * inv_f;
    int f0 = (int)floorf(fi) + 1;
    f0 = f0 < 0 ? 0 : (f0 > N_FZ - 2 ? N_FZ - 2 : f0);

    const float*  gB = gT + (size_t)f0 * N_ALPHA * N_TINT;
    const float2* Pt = Pc + (size_t)t * N_ORB;

    // ---- Phase A: load, histogram, scan, scatter ----
    hist[tid] = 0; hist[tid + 256] = 0;
    __syncthreads();

    float2 v[4];
    int    bin[4];
#pragma unroll
    for (int k = 0; k < 4; ++k) {
        v[k] = Pt[tid + k * 256];
        int s = (int)v[k].x;                 // u >= 0; dead orbits have u=0
        bin[k] = s > 510 ? 510 : s;
        atomicAdd(&hist[bin[k]], 1);
    }
    __syncthreads();

    if (tid < 64) {                          // wave 0: exclusive scan, 512 bins
        int pre[8]; int run = 0;
#pragma unroll
        for (int j = 0; j < 8; ++j) { pre[j] = run; run += hist[tid * 8 + j]; }
        int inc = run;
#pragma unroll
        for (int d = 1; d < 64; d <<= 1) {
            int n = __shfl_up(inc, d);
            if (lane >= d) inc += n;
        }
        int excl = inc - run;
#pragma unroll
        for (int j = 0; j < 8; ++j) histPS[tid * 8 + j] = excl + pre[j];
    }
    __syncthreads();

#pragma unroll
    for (int k = 0; k < 4; ++k) {
        int pos = atomicAdd(&histPS[bin[k]], 1);
        Psort[pos] = v[k];
    }
    __syncthreads();

    // ---- Phase B: orbit-serial walk, lane = tint ----
    int base = w * 256;
    int cnt = 0;
    float g0 = 0.0f, g1 = 0.0f, dg = 0.0f;
    int cur = -2;

    for (int ib = 0; ib < 64; ++ib) {
        float2 p0 = Psort[base + ib * 4 + 0];
        float2 p1 = Psort[base + ib * 4 + 1];
        float2 p2 = Psort[base + ib * 4 + 2];
        float2 p3 = Psort[base + ib * 4 + 3];
#pragma unroll
        for (int j = 0; j < 4; ++j) {
            float2 p = j == 0 ? p0 : (j == 1 ? p1 : (j == 2 ? p2 : p3));
            float u = p.x, dm = p.y;
            int su = __builtin_amdgcn_readfirstlane((int)u);  // wave-uniform
            if (su != cur) {                                  // scalar branch
                if (su != cur + 1) g0 = gB[su * N_TINT + lane];
                else               g0 = g1;                   // row-advance reuse
                g1 = gB[su * N_TINT + N_TINT + lane];
                dg = g1 - g0;
                cur = su;
            }
            cnt += dm < fmaf(u - (float)su, dg, g0);
        }
    }

    red[w * 64 + lane] = cnt;
    __syncthreads();
    if (tid < 64) {
        int tot = red[tid] + red[64 + tid] + red[128 + tid] + red[192 + tid];
        out[(size_t)t * N_TINT + tid] = (float)tot * (1.0f / 1024.0f);
    }
}

// ---------------------------------------------------------------------------
extern "C" void kernel_launch(void* const* d_in, const int* in_sizes, int n_in,
                              void* d_out, int out_size, void* d_ws, size_t ws_size,
                              hipStream_t stream) {
    const float* alpha   = (const float*)d_in[0];
    const float* dMag    = (const float*)d_in[1];
    const float* fZ_vals = (const float*)d_in[2];
    const float* kEZ_val = (const float*)d_in[3];
    const float* grid    = (const float*)d_in[4];
    const float* fZs     = (const float*)d_in[5];
    const float* kEZs    = (const float*)d_in[6];
    const float* alphas  = (const float*)d_in[7];
    float*  out = (float*)d_out;

    float*  gT = (float*)d_ws;
    float2* Pc = (float2*)((char*)d_ws + GT_BYTES);

    stage_inputs<<<dim3(192 + 1024), 256, 0, stream>>>(
        grid, kEZs, kEZ_val, alpha, dMag, alphas, gT, Pc);
    pdet_main<<<dim3(NTIMES), 256, 0, stream>>>(fZ_vals, fZs, gT, Pc, out);
}

// Round 5
// 111.439 us; speedup vs baseline: 1.2275x; 1.2275x over previous
//
#include <hip/hip_runtime.h>
#include <math.h>

#define N_ORB   1024
#define NTIMES  1024
#define N_FZ    24
#define N_KEZ   6
#define N_TINT  64
#define N_ALPHA 512

#define SL_STRIDE 33   // padded dword stride for LDS slice rows (bank-conflict-free)

// Workspace:
//   gT : [N_FZ][N_ALPHA][N_TINT] float  = 3,145,728 B  (grid slice, transposed)
//   Pc : [NTIMES][N_ORB] float2         = 8,388,608 B  {u = s + dalpha, dMagEff}
#define GT_BYTES (N_FZ * N_ALPHA * N_TINT * 4)

// ---------------------------------------------------------------------------
// Kernel 1: fused staging. Blocks 0..191: gT transpose (64tint x 64s tile).
// Blocks 192..1215: Pc build from alpha/dMag, 32x32 (o,t) LDS transpose.
// ---------------------------------------------------------------------------
__global__ __launch_bounds__(256) void stage_inputs(
    const float* __restrict__ grid, const float* __restrict__ kEZs,
    const float* __restrict__ kEZ_val_p, const float* __restrict__ alpha,
    const float* __restrict__ dMag, const float* __restrict__ alphas,
    float* __restrict__ gT, float2* __restrict__ Pc)
{
    __shared__ float lds[64 * 65];          // gT branch; Pc branch aliases

    int b = blockIdx.x;
    if (b < 192) {
        // ---- gT[fz][s][tint] = grid[fz][kez][tint][s] ----
        float kv = kEZ_val_p[0];
        int cnt = 0;
#pragma unroll
        for (int i = 0; i < N_KEZ; ++i) cnt += (kEZs[i] <= kv) ? 1 : 0;
        int kez = cnt - 1;                   // searchsorted(right) - 1
        kez = kez < 0 ? 0 : (kez > N_KEZ - 1 ? N_KEZ - 1 : kez);

        int fz = b >> 3, sc = b & 7;
        int w = threadIdx.x >> 6, lane = threadIdx.x & 63;
        const float* gsrc = grid + ((size_t)fz * N_KEZ + kez) * N_TINT * N_ALPHA;

#pragma unroll
        for (int r = 0; r < 16; ++r) {
            int tint = w * 16 + r;
            lds[tint * 65 + lane] = gsrc[(size_t)tint * N_ALPHA + sc * 64 + lane];
        }
        __syncthreads();
#pragma unroll
        for (int r = 0; r < 16; ++r) {
            int sl = w * 16 + r;
            gT[((size_t)fz * N_ALPHA + sc * 64 + sl) * N_TINT + lane] = lds[lane * 65 + sl];
        }
    } else {
        // ---- Pc[t][o] = {u, dmEff}, 32x32 tile ----
        float* ut = lds;                     // [32][33]
        float* dt = lds + 1056;

        int u = b - 192;                     // 0..1023
        int t0 = (u & 31) * 32, o0 = (u >> 5) * 32;
        int row = threadIdx.x >> 5, col = threadIdx.x & 31;

        float al0 = alphas[0], al1 = alphas[N_ALPHA - 1];
        float la0 = log10f(al0);
        float inv_step = 1.0f / (log10f(alphas[1]) - la0);

#pragma unroll
        for (int r = 0; r < 4; ++r) {
            int ol = r * 8 + row;
            size_t idx = (size_t)(o0 + ol) * NTIMES + t0 + col;
            float a = alpha[idx];
            float d = dMag[idx];
            float a_ind = (log10f(a) - la0) * inv_step;
            int a0i = (int)a_ind;            // trunc toward zero == astype(int32)
            a0i = a0i < 0 ? 0 : (a0i > N_ALPHA - 1 ? N_ALPHA - 1 : a0i);
            float dal = a_ind - (float)a0i;  // vs clipped a0 (faithful)
            int s = a0i > N_ALPHA - 2 ? N_ALPHA - 2 : a0i;   // dynamic_slice clamp
            bool geom = (a >= al0) && (a <= al1);
            float uv = (float)s + dal;       // u packs (s, dalpha); validated R4
            uv = fminf(fmaxf(uv, 0.0f), 510.999f);
            if (!geom) uv = 0.0f;            // dead: dm=INF kills the compare
            ut[ol * 33 + col] = uv;
            dt[ol * 33 + col] = geom ? d : __builtin_inff();
        }
        __syncthreads();
#pragma unroll
        for (int r = 0; r < 4; ++r) {
            int tl = r * 8 + row;
            float2 v;
            v.x = ut[col * 33 + tl];
            v.y = dt[col * 33 + tl];
            Pc[(size_t)(t0 + tl) * N_ORB + o0 + col] = v;
        }
    }
}

// ---------------------------------------------------------------------------
// Kernel 2: block = (t, tint-half). Stage the full f0 slice for 32 tints
// into LDS ([512 s][33-padded tint32], 67.6 KB) + the 8 KB Pc[t] row ->
// 76 KB LDS, 2 blocks/CU. Main loop: lane = (orbit-parity<<5) | tint;
// each wave-instr handles 2 orbits x 32 tints; per step one broadcast
// ds_read_b64 + one ds_read2_b32 (conflict-free) + ~9 VALU. No sort, no
// atomics, no branches, no global loads in the loop.
// ---------------------------------------------------------------------------
__global__ __launch_bounds__(256) void pdet_main(
    const float* __restrict__ fZ_vals, const float* __restrict__ fZs,
    const float* __restrict__ gT, const float2* __restrict__ Pc,
    float* __restrict__ out)
{
    __shared__ float  sl[N_ALPHA * SL_STRIDE];   // 67,584 B
    __shared__ float2 PcL[N_ORB];                // 8,192 B
    __shared__ int    red[128];

    int t = blockIdx.x >> 1;
    int h = blockIdx.x & 1;                      // tint half
    int tid = threadIdx.x;

    float lf0 = log10f(fZs[0]);
    float inv_f = 1.0f / (log10f(fZs[1]) - lf0);
    float fi = (log10f(fZ_vals[t]) - lf0) * inv_f;
    int f0 = (int)floorf(fi) + 1;
    f0 = f0 < 0 ? 0 : (f0 > N_FZ - 2 ? N_FZ - 2 : f0);

    const float*  gB = gT + (size_t)f0 * N_ALPHA * N_TINT + h * 32;
    const float2* Pt = Pc + (size_t)t * N_ORB;

    // ---- stage grid slice half: 512 rows x 32 tints, padded stride 33 ----
    {
        int srow = tid >> 3;          // 0..31 per iter
        int jj   = tid & 7;           // float4 index within 32-tint row
#pragma unroll
        for (int it = 0; it < 16; ++it) {
            int s = it * 32 + srow;
            float4 g = *reinterpret_cast<const float4*>(gB + (size_t)s * N_TINT + jj * 4);
            float* dst = &sl[s * SL_STRIDE + jj * 4];
            dst[0] = g.x; dst[1] = g.y; dst[2] = g.z; dst[3] = g.w;
        }
    }
    // ---- stage Pc row ----
#pragma unroll
    for (int it = 0; it < 4; ++it)
        PcL[it * 256 + tid] = Pt[it * 256 + tid];
    __syncthreads();

    // ---- main loop ----
    int w = tid >> 6, lane = tid & 63;
    int half = lane >> 5;             // orbit parity
    int j    = lane & 31;             // tint within half

    int obase = w * 256 + half;       // wave w owns orbits [w*256, w*256+256)
    int cnt = 0;

#pragma unroll 8
    for (int k = 0; k < 128; ++k) {
        float2 p = PcL[obase + 2 * k];          // broadcast per 32-lane half
        float u = p.x, dm = p.y;
        int su = (int)u;                         // 0..510
        const float* r0 = &sl[su * SL_STRIDE + j];
        float g0 = r0[0];
        float g1 = r0[SL_STRIDE];                // row s+1 (ds_read2_b32)
        cnt += dm < fmaf(u - (float)su, g1 - g0, g0);
    }

    // ---- reduce: lane j and j+32 hold the same tint ----
    cnt += __shfl_xor(cnt, 32);
    if (lane < 32) red[w * 32 + lane] = cnt;
    __syncthreads();
    if (tid < 32) {
        int tot = red[tid] + red[32 + tid] + red[64 + tid] + red[96 + tid];
        out[(size_t)t * N_TINT + h * 32 + tid] = (float)tot * (1.0f / 1024.0f);
    }
}

// ---------------------------------------------------------------------------
extern "C" void kernel_launch(void* const* d_in, const int* in_sizes, int n_in,
                              void* d_out, int out_size, void* d_ws, size_t ws_size,
                              hipStream_t stream) {
    const float* alpha   = (const float*)d_in[0];
    const float* dMag    = (const float*)d_in[1];
    const float* fZ_vals = (const float*)d_in[2];
    const float* kEZ_val = (const float*)d_in[3];
    const float* grid    = (const float*)d_in[4];
    const float* fZs     = (const float*)d_in[5];
    const float* kEZs    = (const float*)d_in[6];
    const float* alphas  = (const float*)d_in[7];
    float*  out = (float*)d_out;

    float*  gT = (float*)d_ws;
    float2* Pc = (float2*)((char*)d_ws + GT_BYTES);

    stage_inputs<<<dim3(192 + 1024), 256, 0, stream>>>(
        grid, kEZs, kEZ_val, alpha, dMag, alphas, gT, Pc);
    pdet_main<<<dim3(NTIMES * 2), 256, 0, stream>>>(fZ_vals, fZs, gT, Pc, out);
}